// Round 1
// baseline (1493.305 us; speedup 1.0000x reference)
//
#include <hip/hip_runtime.h>
#include <math.h>

#define NB 2
#define NN 1024
#define HH 768
#define MAXW 30
#define WD 20
#define KTOP 409

constexpr int MT = 64, NT = 256, KT = 32;
constexpr int ASTR = MT + 4;   // 68 -> 272B row stride (16B aligned)
constexpr int BSTR = NT + 4;   // 260 -> 1040B row stride (16B aligned)

__device__ __forceinline__ float gelu_f(float z) {
  return 0.5f * z * (1.0f + erff(z * 0.70710678118654752440f));
}

__device__ __forceinline__ unsigned f2key(float f) {
  unsigned u = __float_as_uint(f);
  return (u & 0x80000000u) ? ~u : (u | 0x80000000u);
}

// ---------------- lengths = mask.sum(-1) ----------------
__global__ void len_kernel(const int* __restrict__ mask, int* __restrict__ lengths) {
  __shared__ int red[256];
  for (int b = 0; b < NB; ++b) {
    int s = 0;
    for (int i = threadIdx.x; i < NN; i += 256) s += mask[b * NN + i];
    red[threadIdx.x] = s;
    __syncthreads();
    for (int off = 128; off > 0; off >>= 1) {
      if (threadIdx.x < off) red[threadIdx.x] += red[threadIdx.x + off];
      __syncthreads();
    }
    if (threadIdx.x == 0) lengths[b] = red[0];
    __syncthreads();
  }
}

// ---------------- R[w,h] = b1[h] + width_emb[w] @ W1[2304:2324] ----------------
__global__ void r_kernel(const float* __restrict__ wemb, const float* __restrict__ W1,
                         const float* __restrict__ b1, float* __restrict__ R) {
  int w = blockIdx.x;
  for (int h = threadIdx.x; h < HH; h += 256) {
    float acc = b1[h];
    for (int j = 0; j < WD; ++j)
      acc = fmaf(wemb[w * WD + j], W1[(size_t)(3 * HH + j) * HH + h], acc);
    R[w * HH + h] = acc;
  }
}

// ---------------- P = emb @ W1[0:768], Q = emb @ W1[768:1536] ----------------
__global__ __launch_bounds__(256) void pq_kernel(
    const float* __restrict__ emb, const float* __restrict__ W1,
    float* __restrict__ P, float* __restrict__ Q) {
  __shared__ float As[KT][ASTR];
  __shared__ float Bs[KT][BSTR];
  const int tile = blockIdx.x;      // 32 tiles of 64 rows over B*N=2048
  const int yb = blockIdx.y;        // 0..5
  const bool isQ = (yb >= 3);
  const int hb = (yb - (isQ ? 3 : 0)) * NT;
  const float* Bbase = W1 + (isQ ? (size_t)HH * HH : 0);
  float* Obase = isQ ? Q : P;
  const int tid = threadIdx.x;
  const int th = tid & 31, tw = tid >> 5;
  const int m0 = tid >> 3, m1 = m0 + 32;
  const int d0 = (tid & 7) << 2;
  const size_t r0 = (size_t)(tile * MT + m0) * HH;
  const size_t r1 = (size_t)(tile * MT + m1) * HH;
  const int bc = (tid & 63) << 2;
  const int br = tid >> 6;

  float acc[8][8];
#pragma unroll
  for (int i = 0; i < 8; ++i)
#pragma unroll
    for (int j = 0; j < 8; ++j) acc[i][j] = 0.f;

  for (int kt = 0; kt < HH; kt += KT) {
    float4 x0 = *reinterpret_cast<const float4*>(emb + r0 + kt + d0);
    float4 x1 = *reinterpret_cast<const float4*>(emb + r1 + kt + d0);
    float4 bw[8];
#pragma unroll
    for (int r = 0; r < 8; ++r)
      bw[r] = *reinterpret_cast<const float4*>(Bbase + (size_t)(kt + br + 4 * r) * HH + hb + bc);
    __syncthreads();
    As[d0 + 0][m0] = x0.x; As[d0 + 1][m0] = x0.y; As[d0 + 2][m0] = x0.z; As[d0 + 3][m0] = x0.w;
    As[d0 + 0][m1] = x1.x; As[d0 + 1][m1] = x1.y; As[d0 + 2][m1] = x1.z; As[d0 + 3][m1] = x1.w;
#pragma unroll
    for (int r = 0; r < 8; ++r)
      *reinterpret_cast<float4*>(&Bs[br + 4 * r][bc]) = bw[r];
    __syncthreads();
#pragma unroll
    for (int d = 0; d < KT; ++d) {
      const float4 a0 = *reinterpret_cast<const float4*>(&As[d][tw * 4]);
      const float4 a1 = *reinterpret_cast<const float4*>(&As[d][tw * 4 + 32]);
      const float4 b0 = *reinterpret_cast<const float4*>(&Bs[d][th * 4]);
      const float4 b1v = *reinterpret_cast<const float4*>(&Bs[d][th * 4 + 128]);
      const float av[8] = {a0.x, a0.y, a0.z, a0.w, a1.x, a1.y, a1.z, a1.w};
      const float bv[8] = {b0.x, b0.y, b0.z, b0.w, b1v.x, b1v.y, b1v.z, b1v.w};
#pragma unroll
      for (int mi = 0; mi < 8; ++mi)
#pragma unroll
        for (int ni = 0; ni < 8; ++ni)
          acc[mi][ni] = fmaf(av[mi], bv[ni], acc[mi][ni]);
    }
  }
#pragma unroll
  for (int mi = 0; mi < 8; ++mi) {
    const int m = tw * 4 + (mi & 3) + ((mi >> 2) << 5);
    float* op = Obase + (size_t)(tile * MT + m) * HH + hb;
    *reinterpret_cast<float4*>(op + th * 4) = make_float4(acc[mi][0], acc[mi][1], acc[mi][2], acc[mi][3]);
    *reinterpret_cast<float4*>(op + th * 4 + 128) = make_float4(acc[mi][4], acc[mi][5], acc[mi][6], acc[mi][7]);
  }
}

// ---------------- main span MLP: (x*y)@W1c + P + Q + R -> gelu -> partial score / h out ----------------
template <bool GATHER>
__global__ __launch_bounds__(256) void span_mlp_kernel(
    const float* __restrict__ emb, const int* __restrict__ spans,
    const float* __restrict__ W1, const float* __restrict__ w_s,
    const float* __restrict__ P, const float* __restrict__ Q,
    const float* __restrict__ R, const int* __restrict__ sel,
    float* __restrict__ outp, int S) {
  __shared__ float As[KT][ASTR];
  __shared__ float Bs[KT][BSTR];
  __shared__ int ssm[MT], eem[MT], wwm[MT], vvm[MT];

  const int tile = blockIdx.x;
  const int hb = blockIdx.y * NT;
  const int b = blockIdx.z;
  const int tid = threadIdx.x;
  const int th = tid & 31, tw = tid >> 5;

  if (tid < MT) {
    int s = 0, e = 0, valid = 0;
    if (GATHER) {
      int j = tile * MT + tid;
      if (j < KTOP) { int i = sel[b * KTOP + j]; s = spans[2 * i]; e = spans[2 * i + 1]; valid = 1; }
    } else {
      int g = tile * MT + tid;
      if (g < S) { s = spans[2 * g]; e = spans[2 * g + 1]; valid = 1; }
    }
    ssm[tid] = s; eem[tid] = e; wwm[tid] = e - s; vvm[tid] = valid;
  }
  __syncthreads();

  const int m0 = tid >> 3, m1 = m0 + 32;
  const int d0 = (tid & 7) << 2;
  const size_t ebase = (size_t)b * NN * HH;
  const size_t rx0 = ebase + (size_t)ssm[m0] * HH;
  const size_t ry0 = ebase + (size_t)eem[m0] * HH;
  const size_t rx1 = ebase + (size_t)ssm[m1] * HH;
  const size_t ry1 = ebase + (size_t)eem[m1] * HH;

  const float* W1c = W1 + (size_t)(2 * HH) * HH;  // rows 1536..2303
  const int bc = (tid & 63) << 2;
  const int br = tid >> 6;

  float acc[8][8];
#pragma unroll
  for (int i = 0; i < 8; ++i)
#pragma unroll
    for (int j = 0; j < 8; ++j) acc[i][j] = 0.f;

  for (int kt = 0; kt < HH; kt += KT) {
    float4 x0 = *reinterpret_cast<const float4*>(emb + rx0 + kt + d0);
    float4 y0 = *reinterpret_cast<const float4*>(emb + ry0 + kt + d0);
    float4 x1 = *reinterpret_cast<const float4*>(emb + rx1 + kt + d0);
    float4 y1 = *reinterpret_cast<const float4*>(emb + ry1 + kt + d0);
    float4 bw[8];
#pragma unroll
    for (int r = 0; r < 8; ++r)
      bw[r] = *reinterpret_cast<const float4*>(W1c + (size_t)(kt + br + 4 * r) * HH + hb + bc);
    __syncthreads();
    As[d0 + 0][m0] = x0.x * y0.x; As[d0 + 1][m0] = x0.y * y0.y;
    As[d0 + 2][m0] = x0.z * y0.z; As[d0 + 3][m0] = x0.w * y0.w;
    As[d0 + 0][m1] = x1.x * y1.x; As[d0 + 1][m1] = x1.y * y1.y;
    As[d0 + 2][m1] = x1.z * y1.z; As[d0 + 3][m1] = x1.w * y1.w;
#pragma unroll
    for (int r = 0; r < 8; ++r)
      *reinterpret_cast<float4*>(&Bs[br + 4 * r][bc]) = bw[r];
    __syncthreads();
#pragma unroll
    for (int d = 0; d < KT; ++d) {
      const float4 a0 = *reinterpret_cast<const float4*>(&As[d][tw * 4]);
      const float4 a1 = *reinterpret_cast<const float4*>(&As[d][tw * 4 + 32]);
      const float4 b0 = *reinterpret_cast<const float4*>(&Bs[d][th * 4]);
      const float4 b1v = *reinterpret_cast<const float4*>(&Bs[d][th * 4 + 128]);
      const float av[8] = {a0.x, a0.y, a0.z, a0.w, a1.x, a1.y, a1.z, a1.w};
      const float bv[8] = {b0.x, b0.y, b0.z, b0.w, b1v.x, b1v.y, b1v.z, b1v.w};
#pragma unroll
      for (int mi = 0; mi < 8; ++mi)
#pragma unroll
        for (int ni = 0; ni < 8; ++ni)
          acc[mi][ni] = fmaf(av[mi], bv[ni], acc[mi][ni]);
    }
  }
  __syncthreads();  // all As/Bs reads done before sred reuse

  float wv[8];
  if (!GATHER) {
    const float4 w0 = *reinterpret_cast<const float4*>(w_s + hb + th * 4);
    const float4 w1 = *reinterpret_cast<const float4*>(w_s + hb + th * 4 + 128);
    wv[0] = w0.x; wv[1] = w0.y; wv[2] = w0.z; wv[3] = w0.w;
    wv[4] = w1.x; wv[5] = w1.y; wv[6] = w1.z; wv[7] = w1.w;
  }
  float* sred = (float*)As;

#pragma unroll
  for (int mi = 0; mi < 8; ++mi) {
    const int m = tw * 4 + (mi & 3) + ((mi >> 2) << 5);
    float psum = 0.f;
    if (vvm[m]) {
      const int s = ssm[m], e = eem[m], w = wwm[m];
      const float* Pp = P + ((size_t)b * NN + s) * HH + hb;
      const float* Qp = Q + ((size_t)b * NN + e) * HH + hb;
      const float* Rp = R + (size_t)w * HH + hb;
      const float4 p0 = *reinterpret_cast<const float4*>(Pp + th * 4);
      const float4 p1 = *reinterpret_cast<const float4*>(Pp + th * 4 + 128);
      const float4 q0 = *reinterpret_cast<const float4*>(Qp + th * 4);
      const float4 q1 = *reinterpret_cast<const float4*>(Qp + th * 4 + 128);
      const float4 r0 = *reinterpret_cast<const float4*>(Rp + th * 4);
      const float4 r1 = *reinterpret_cast<const float4*>(Rp + th * 4 + 128);
      const float pz[8] = {p0.x + q0.x + r0.x, p0.y + q0.y + r0.y,
                           p0.z + q0.z + r0.z, p0.w + q0.w + r0.w,
                           p1.x + q1.x + r1.x, p1.y + q1.y + r1.y,
                           p1.z + q1.z + r1.z, p1.w + q1.w + r1.w};
      float gl[8];
#pragma unroll
      for (int ni = 0; ni < 8; ++ni) gl[ni] = gelu_f(acc[mi][ni] + pz[ni]);
      if (GATHER) {
        const int jj = tile * MT + m;
        float* op = outp + (size_t)(b * KTOP + jj) * HH + hb;
        *reinterpret_cast<float4*>(op + th * 4) = make_float4(gl[0], gl[1], gl[2], gl[3]);
        *reinterpret_cast<float4*>(op + th * 4 + 128) = make_float4(gl[4], gl[5], gl[6], gl[7]);
      } else {
#pragma unroll
        for (int ni = 0; ni < 8; ++ni) psum = fmaf(gl[ni], wv[ni], psum);
      }
    }
    if (!GATHER) sred[m * 33 + th] = psum;
  }
  if (!GATHER) {
    __syncthreads();
    if (tid < MT) {
      float t = 0.f;
#pragma unroll
      for (int j = 0; j < 32; ++j) t += sred[tid * 33 + j];
      const int g = tile * MT + tid;
      if (g < S)
        outp[(size_t)blockIdx.y * ((size_t)NB * S) + (size_t)b * S + g] = t;
    }
  }
}

// ---------------- combine partials + bias + mask penalty ----------------
__global__ void combine_kernel(const float* __restrict__ sp, const int* __restrict__ spans,
                               const float* __restrict__ b_s, const int* __restrict__ lengths,
                               float* __restrict__ scores, int S) {
  int idx = blockIdx.x * 256 + threadIdx.x;
  if (idx >= NB * S) return;
  int b = idx / S, i = idx - b * S;
  size_t st = (size_t)NB * S;
  float v = sp[idx] + sp[st + idx] + sp[2 * st + idx] + b_s[0];
  if (spans[2 * i + 1] >= lengths[b]) v += -1000000.0f;
  scores[idx] = v;
}

// ---------------- exact top-k: radix select + index-ordered compaction ----------------
__global__ __launch_bounds__(1024) void topk_kernel(
    const float* __restrict__ scores, const int* __restrict__ spans,
    const int* __restrict__ kptr, int S,
    float* __restrict__ out_scores, float* __restrict__ out_spans,
    int* __restrict__ sel) {
  const int b = blockIdx.x;
  const int tid = threadIdx.x;
  const float* sc = scores + (size_t)b * S;
  const int k = kptr[0];

  __shared__ unsigned hist[256];
  __shared__ unsigned sh_prefix;
  __shared__ int sh_remaining;
  __shared__ int wave_eq[16], wave_sel[16];
  __shared__ int selbase, eqbase;

  unsigned prefix = 0;
  int remaining = k;
  for (int round = 0; round < 4; ++round) {
    const int shift = 24 - 8 * round;
    if (tid < 256) hist[tid] = 0;
    __syncthreads();
    for (int i = tid; i < S; i += 1024) {
      unsigned key = f2key(sc[i]);
      if (round == 0 || (key >> (shift + 8)) == prefix)
        atomicAdd(&hist[(key >> shift) & 255u], 1u);
    }
    __syncthreads();
    if (tid == 0) {
      int cum = 0;
      for (int bin = 255; bin >= 0; --bin) {
        int c = (int)hist[bin];
        if (cum + c >= remaining) {
          sh_prefix = (prefix << 8) | (unsigned)bin;
          sh_remaining = remaining - cum;
          break;
        }
        cum += c;
      }
    }
    __syncthreads();
    prefix = sh_prefix;
    remaining = sh_remaining;
    __syncthreads();
  }
  const unsigned pivot = prefix;
  const int m_eq = remaining;  // # of ==pivot to take, lowest index first

  if (tid == 0) { selbase = 0; eqbase = 0; }
  __syncthreads();

  const int lane = tid & 63, wv = tid >> 6;
  for (int base = 0; base < S; base += 1024) {
    const int i = base + tid;
    const bool inb = (i < S);
    const float sval = inb ? sc[i] : 0.f;
    const unsigned key = inb ? f2key(sval) : 0u;
    const bool gt = inb && (key > pivot);
    const bool eq = inb && (key == pivot);

    unsigned long long mm = __ballot(eq);
    int eqpre = __popcll(mm & ((1ull << lane) - 1ull));
    if (lane == 0) wave_eq[wv] = __popcll(mm);
    __syncthreads();
    int eqpref = 0, eqtot = 0;
#pragma unroll
    for (int w2 = 0; w2 < 16; ++w2) {
      int c = wave_eq[w2];
      if (w2 < wv) eqpref += c;
      eqtot += c;
    }
    const bool take_eq = eq && (eqbase + eqpref + eqpre < m_eq);
    const bool sf = gt || take_eq;

    unsigned long long sm = __ballot(sf);
    int spre = __popcll(sm & ((1ull << lane) - 1ull));
    if (lane == 0) wave_sel[wv] = __popcll(sm);
    __syncthreads();
    int spref = 0, stot = 0;
#pragma unroll
    for (int w2 = 0; w2 < 16; ++w2) {
      int c = wave_sel[w2];
      if (w2 < wv) spref += c;
      stot += c;
    }
    if (sf) {
      const int j = selbase + spref + spre;
      out_scores[b * KTOP + j] = sval;
      out_spans[(b * KTOP + j) * 2 + 0] = (float)spans[2 * i];
      out_spans[(b * KTOP + j) * 2 + 1] = (float)spans[2 * i + 1];
      sel[b * KTOP + j] = i;
    }
    __syncthreads();
    if (tid == 0) { selbase += stot; eqbase += eqtot; }
    __syncthreads();
  }
}

extern "C" void kernel_launch(void* const* d_in, const int* in_sizes, int n_in,
                              void* d_out, int out_size, void* d_ws, size_t ws_size,
                              hipStream_t stream) {
  const float* emb = (const float*)d_in[0];
  const int* mask = (const int*)d_in[1];
  const int* spans = (const int*)d_in[2];
  const float* wemb = (const float*)d_in[3];
  const float* W1 = (const float*)d_in[4];
  const float* b1 = (const float*)d_in[5];
  const float* w_s = (const float*)d_in[6];
  const float* b_s = (const float*)d_in[7];
  const int* kptr = (const int*)d_in[8];
  const int S = in_sizes[2] / 2;  // 30285
  float* out = (float*)d_out;

  // workspace carve (floats)
  float* ws = (float*)d_ws;
  float* Pb = ws;
  float* Qb = Pb + (size_t)NB * NN * HH;
  float* Rb = Qb + (size_t)NB * NN * HH;
  float* spart = Rb + (size_t)MAXW * HH;            // 3 * NB * S partial scores
  float* scoresb = spart + 3 * (size_t)NB * S;      // NB * S combined scores
  int* selb = (int*)(scoresb + (size_t)NB * S);     // NB * KTOP
  int* lengthsb = selb + NB * KTOP;                 // NB

  // output layout: embs | scores | spans (all as float)
  const size_t OFF1 = (size_t)NB * KTOP * HH;       // 628224
  const size_t OFF2 = OFF1 + (size_t)NB * KTOP;     // 629042

  len_kernel<<<dim3(1), dim3(256), 0, stream>>>(mask, lengthsb);
  r_kernel<<<dim3(MAXW), dim3(256), 0, stream>>>(wemb, W1, b1, Rb);
  pq_kernel<<<dim3((NB * NN) / MT, 6), dim3(256), 0, stream>>>(emb, W1, Pb, Qb);
  span_mlp_kernel<false><<<dim3((S + MT - 1) / MT, 3, NB), dim3(256), 0, stream>>>(
      emb, spans, W1, w_s, Pb, Qb, Rb, nullptr, spart, S);
  combine_kernel<<<dim3((NB * S + 255) / 256), dim3(256), 0, stream>>>(
      spart, spans, b_s, lengthsb, scoresb, S);
  topk_kernel<<<dim3(NB), dim3(1024), 0, stream>>>(
      scoresb, spans, kptr, S, out + OFF1, out + OFF2, selb);
  span_mlp_kernel<true><<<dim3((KTOP + MT - 1) / MT, 3, NB), dim3(256), 0, stream>>>(
      emb, spans, W1, nullptr, Pb, Qb, Rb, selb, out, S);
}

// Round 2
// 890.475 us; speedup vs baseline: 1.6770x; 1.6770x over previous
//
#include <hip/hip_runtime.h>
#include <math.h>

#define NB 2
#define NN 1024
#define HH 768
#define MAXW 30
#define KTOP 409
#define BANDCAP 256
#define BAND_TAU 1e-3f

typedef __attribute__((ext_vector_type(4))) float f32x4;
typedef __attribute__((ext_vector_type(8))) __bf16 bf16x8;
typedef __attribute__((ext_vector_type(8))) unsigned short us8;

// round-1 fp32 tile constants (pq + gather kernels)
constexpr int MT = 64, NT = 256, KT = 32;
constexpr int ASTR = MT + 4;
constexpr int BSTR = NT + 4;

__device__ __forceinline__ float gelu_f(float z) {
  return 0.5f * z * (1.0f + erff(z * 0.70710678118654752440f));
}

__device__ __forceinline__ unsigned f2key(float f) {
  unsigned u = __float_as_uint(f);
  return (u & 0x80000000u) ? ~u : (u | 0x80000000u);
}
__device__ __forceinline__ float key2f(unsigned k) {
  unsigned u = (k & 0x80000000u) ? (k & 0x7fffffffu) : ~k;
  return __uint_as_float(u);
}
// fp32 -> bf16 round-to-nearest-even, pure integer (no __bf16 scalar codegen reliance)
__device__ __forceinline__ unsigned short f2bf_rn(float f) {
  unsigned u = __float_as_uint(f);
  unsigned r = u + 0x7fffu + ((u >> 16) & 1u);
  return (unsigned short)(r >> 16);
}
__device__ __forceinline__ float bf2f(unsigned short h) {
  return __uint_as_float(((unsigned)h) << 16);
}

// ---------------- lengths ----------------
__global__ void len_kernel(const int* __restrict__ mask, int* __restrict__ lengths) {
  __shared__ int red[256];
  for (int b = 0; b < NB; ++b) {
    int s = 0;
    for (int i = threadIdx.x; i < NN; i += 256) s += mask[b * NN + i];
    red[threadIdx.x] = s;
    __syncthreads();
    for (int off = 128; off > 0; off >>= 1) {
      if (threadIdx.x < off) red[threadIdx.x] += red[threadIdx.x + off];
      __syncthreads();
    }
    if (threadIdx.x == 0) lengths[b] = red[0];
    __syncthreads();
  }
}

// ---------------- R[w,h] ----------------
__global__ void r_kernel(const float* __restrict__ wemb, const float* __restrict__ W1,
                         const float* __restrict__ b1, float* __restrict__ R) {
  int w = blockIdx.x;
  for (int h = threadIdx.x; h < HH; h += 256) {
    float acc = b1[h];
    for (int j = 0; j < 20; ++j)
      acc = fmaf(wemb[w * 20 + j], W1[(size_t)(3 * HH + j) * HH + h], acc);
    R[w * HH + h] = acc;
  }
}

// ---------------- split W1c into bf16 hi/lo, pre-tiled [hb][kt][n128][k32] ----------------
__global__ __launch_bounds__(256) void prep_b_kernel(const float* __restrict__ W1,
                                                     unsigned short* __restrict__ Bthi,
                                                     unsigned short* __restrict__ Btlo) {
  __shared__ float tile[32][128];
  const int ktb = blockIdx.x;  // 0..23
  const int hb = blockIdx.y;   // 0..5
  const float* W1c = W1 + (size_t)(2 * HH) * HH;
  const int t = threadIdx.x;
  {
    int kk = t >> 3, n16 = (t & 7) * 16;
    const float* src = W1c + (size_t)(ktb * 32 + kk) * HH + hb * 128 + n16;
    float4 a = *(const float4*)(src + 0);
    float4 bq = *(const float4*)(src + 4);
    float4 c = *(const float4*)(src + 8);
    float4 d = *(const float4*)(src + 12);
    *(float4*)&tile[kk][n16 + 0] = a;
    *(float4*)&tile[kk][n16 + 4] = bq;
    *(float4*)&tile[kk][n16 + 8] = c;
    *(float4*)&tile[kk][n16 + 12] = d;
  }
  __syncthreads();
  const int n = t >> 1, kh = (t & 1) * 16;
  unsigned short hv[16], lv[16];
#pragma unroll
  for (int j = 0; j < 16; ++j) {
    float v = tile[kh + j][n];
    hv[j] = f2bf_rn(v);
    lv[j] = f2bf_rn(v - bf2f(hv[j]));
  }
  size_t base = (((size_t)hb * 24 + ktb) * 128 + n) * 32 + kh;
  us8 h0, h1, l0, l1;
#pragma unroll
  for (int j = 0; j < 8; ++j) { h0[j] = hv[j]; h1[j] = hv[j + 8]; l0[j] = lv[j]; l1[j] = lv[j + 8]; }
  *(us8*)(Bthi + base) = h0;
  *(us8*)(Bthi + base + 8) = h1;
  *(us8*)(Btlo + base) = l0;
  *(us8*)(Btlo + base + 8) = l1;
}

// ---------------- P/Q (fp32, round-1) ----------------
__global__ __launch_bounds__(256) void pq_kernel(
    const float* __restrict__ emb, const float* __restrict__ W1,
    float* __restrict__ P, float* __restrict__ Q) {
  __shared__ float As[KT][ASTR];
  __shared__ float Bs[KT][BSTR];
  const int tile = blockIdx.x;
  const int yb = blockIdx.y;
  const bool isQ = (yb >= 3);
  const int hb = (yb - (isQ ? 3 : 0)) * NT;
  const float* Bbase = W1 + (isQ ? (size_t)HH * HH : 0);
  float* Obase = isQ ? Q : P;
  const int tid = threadIdx.x;
  const int th = tid & 31, tw = tid >> 5;
  const int m0 = tid >> 3, m1 = m0 + 32;
  const int d0 = (tid & 7) << 2;
  const size_t r0 = (size_t)(tile * MT + m0) * HH;
  const size_t r1 = (size_t)(tile * MT + m1) * HH;
  const int bc = (tid & 63) << 2;
  const int br = tid >> 6;
  float acc[8][8];
#pragma unroll
  for (int i = 0; i < 8; ++i)
#pragma unroll
    for (int j = 0; j < 8; ++j) acc[i][j] = 0.f;
  for (int kt = 0; kt < HH; kt += KT) {
    float4 x0 = *reinterpret_cast<const float4*>(emb + r0 + kt + d0);
    float4 x1 = *reinterpret_cast<const float4*>(emb + r1 + kt + d0);
    float4 bw[8];
#pragma unroll
    for (int r = 0; r < 8; ++r)
      bw[r] = *reinterpret_cast<const float4*>(Bbase + (size_t)(kt + br + 4 * r) * HH + hb + bc);
    __syncthreads();
    As[d0 + 0][m0] = x0.x; As[d0 + 1][m0] = x0.y; As[d0 + 2][m0] = x0.z; As[d0 + 3][m0] = x0.w;
    As[d0 + 0][m1] = x1.x; As[d0 + 1][m1] = x1.y; As[d0 + 2][m1] = x1.z; As[d0 + 3][m1] = x1.w;
#pragma unroll
    for (int r = 0; r < 8; ++r)
      *reinterpret_cast<float4*>(&Bs[br + 4 * r][bc]) = bw[r];
    __syncthreads();
#pragma unroll
    for (int d = 0; d < KT; ++d) {
      const float4 a0 = *reinterpret_cast<const float4*>(&As[d][tw * 4]);
      const float4 a1 = *reinterpret_cast<const float4*>(&As[d][tw * 4 + 32]);
      const float4 b0 = *reinterpret_cast<const float4*>(&Bs[d][th * 4]);
      const float4 b1v = *reinterpret_cast<const float4*>(&Bs[d][th * 4 + 128]);
      const float av[8] = {a0.x, a0.y, a0.z, a0.w, a1.x, a1.y, a1.z, a1.w};
      const float bv[8] = {b0.x, b0.y, b0.z, b0.w, b1v.x, b1v.y, b1v.z, b1v.w};
#pragma unroll
      for (int mi = 0; mi < 8; ++mi)
#pragma unroll
        for (int ni = 0; ni < 8; ++ni)
          acc[mi][ni] = fmaf(av[mi], bv[ni], acc[mi][ni]);
    }
  }
#pragma unroll
  for (int mi = 0; mi < 8; ++mi) {
    const int m = tw * 4 + (mi & 3) + ((mi >> 2) << 5);
    float* op = Obase + (size_t)(tile * MT + m) * HH + hb;
    *reinterpret_cast<float4*>(op + th * 4) = make_float4(acc[mi][0], acc[mi][1], acc[mi][2], acc[mi][3]);
    *reinterpret_cast<float4*>(op + th * 4 + 128) = make_float4(acc[mi][4], acc[mi][5], acc[mi][6], acc[mi][7]);
  }
}

// ---------------- MFMA split-bf16 scoring: (x*y)@W1c -> +P+Q+R -> gelu -> .w_s partials ----------------
__global__ __launch_bounds__(256, 2) void score_mfma_kernel(
    const float* __restrict__ emb, const int* __restrict__ spans,
    const unsigned short* __restrict__ Bthi, const unsigned short* __restrict__ Btlo,
    const float* __restrict__ w_s,
    const float* __restrict__ P, const float* __restrict__ Q, const float* __restrict__ R,
    float* __restrict__ spart, int S) {
  __shared__ unsigned short As_hi[128 * 32], As_lo[128 * 32];
  __shared__ unsigned short Bs_hi[128 * 32], Bs_lo[128 * 32];
  __shared__ int ssm[128], eem[128], wwm[128];
  __shared__ float sred[128 * 2];

  const int tile = blockIdx.x;
  const int hby = blockIdx.y;  // 128-col block, 0..5
  const int b = blockIdx.z;
  const int tid = threadIdx.x;
  const int lane = tid & 63, w = tid >> 6;
  const int wm = w & 1, wn = w >> 1;
  const int lm = lane & 15, lq = lane >> 4;

  if (tid < 128) {
    int g = tile * 128 + tid;
    int gg = g < S ? g : S - 1;
    int s = spans[2 * gg], e = spans[2 * gg + 1];
    ssm[tid] = s; eem[tid] = e; wwm[tid] = e - s;
  }
  __syncthreads();

  const int am = tid >> 1;
  const int kh = (tid & 1) * 16;
  const size_t ebase = (size_t)b * NN * HH;
  const float* xrow = emb + ebase + (size_t)ssm[am] * HH + kh;
  const float* yrow = emb + ebase + (size_t)eem[am] * HH + kh;

  f32x4 acc[4][4];
#pragma unroll
  for (int i = 0; i < 4; ++i)
#pragma unroll
    for (int j = 0; j < 4; ++j) acc[i][j] = (f32x4){0.f, 0.f, 0.f, 0.f};

  const size_t btile0 = (size_t)hby * 24 * 128 * 32;

  for (int ki = 0; ki < 24; ++ki) {
    const int kt = ki * 32;
    float4 xv[4], yv[4];
#pragma unroll
    for (int j = 0; j < 4; ++j) {
      xv[j] = *reinterpret_cast<const float4*>(xrow + kt + j * 4);
      yv[j] = *reinterpret_cast<const float4*>(yrow + kt + j * 4);
    }
    const float4* gBh = reinterpret_cast<const float4*>(Bthi + btile0 + (size_t)ki * 4096);
    const float4* gBl = reinterpret_cast<const float4*>(Btlo + btile0 + (size_t)ki * 4096);
    float4 bh0 = gBh[2 * tid], bh1 = gBh[2 * tid + 1];
    float4 bl0 = gBl[2 * tid], bl1 = gBl[2 * tid + 1];
    __syncthreads();
    // A split-stage
    {
      float px[16];
#pragma unroll
      for (int j = 0; j < 4; ++j) {
        px[4 * j + 0] = xv[j].x * yv[j].x;
        px[4 * j + 1] = xv[j].y * yv[j].y;
        px[4 * j + 2] = xv[j].z * yv[j].z;
        px[4 * j + 3] = xv[j].w * yv[j].w;
      }
      us8 vh0, vh1, vl0, vl1;
#pragma unroll
      for (int j = 0; j < 8; ++j) {
        unsigned short h = f2bf_rn(px[j]);
        vh0[j] = h;
        vl0[j] = f2bf_rn(px[j] - bf2f(h));
        unsigned short h2 = f2bf_rn(px[j + 8]);
        vh1[j] = h2;
        vl1[j] = f2bf_rn(px[j + 8] - bf2f(h2));
      }
      const int ab = am * 32 + kh;
      *(us8*)(As_hi + ab) = vh0;
      *(us8*)(As_hi + ab + 8) = vh1;
      *(us8*)(As_lo + ab) = vl0;
      *(us8*)(As_lo + ab + 8) = vl1;
    }
    ((float4*)Bs_hi)[2 * tid] = bh0;
    ((float4*)Bs_hi)[2 * tid + 1] = bh1;
    ((float4*)Bs_lo)[2 * tid] = bl0;
    ((float4*)Bs_lo)[2 * tid + 1] = bl1;
    __syncthreads();

    bf16x8 ah[4], al[4];
#pragma unroll
    for (int mi = 0; mi < 4; ++mi) {
      const int rA = wm * 64 + mi * 16 + lm;
      ah[mi] = *reinterpret_cast<const bf16x8*>(As_hi + rA * 32 + lq * 8);
      al[mi] = *reinterpret_cast<const bf16x8*>(As_lo + rA * 32 + lq * 8);
    }
#pragma unroll
    for (int ni = 0; ni < 4; ++ni) {
      const int rB = wn * 64 + ni * 16 + lm;
      bf16x8 bh = *reinterpret_cast<const bf16x8*>(Bs_hi + rB * 32 + lq * 8);
      bf16x8 bl = *reinterpret_cast<const bf16x8*>(Bs_lo + rB * 32 + lq * 8);
#pragma unroll
      for (int mi = 0; mi < 4; ++mi) {
        acc[mi][ni] = __builtin_amdgcn_mfma_f32_16x16x32_bf16(ah[mi], bh, acc[mi][ni], 0, 0, 0);
        acc[mi][ni] = __builtin_amdgcn_mfma_f32_16x16x32_bf16(ah[mi], bl, acc[mi][ni], 0, 0, 0);
        acc[mi][ni] = __builtin_amdgcn_mfma_f32_16x16x32_bf16(al[mi], bh, acc[mi][ni], 0, 0, 0);
      }
    }
  }
  __syncthreads();

  const int hbg = hby * 128;
  float wsv[4];
#pragma unroll
  for (int ni = 0; ni < 4; ++ni) wsv[ni] = w_s[hbg + wn * 64 + ni * 16 + lm];

#pragma unroll
  for (int mi = 0; mi < 4; ++mi) {
#pragma unroll
    for (int r = 0; r < 4; ++r) {
      const int rowl = wm * 64 + mi * 16 + lq * 4 + r;
      const int s = ssm[rowl], e = eem[rowl], wd = wwm[rowl];
      const float* Pp = P + ((size_t)b * NN + s) * HH + hbg + wn * 64 + lm;
      const float* Qp = Q + ((size_t)b * NN + e) * HH + hbg + wn * 64 + lm;
      const float* Rp = R + (size_t)wd * HH + hbg + wn * 64 + lm;
      float psum = 0.f;
#pragma unroll
      for (int ni = 0; ni < 4; ++ni) {
        float z = acc[mi][ni][r] + Pp[ni * 16] + Qp[ni * 16] + Rp[ni * 16];
        psum = fmaf(gelu_f(z), wsv[ni], psum);
      }
      psum += __shfl_xor(psum, 1);
      psum += __shfl_xor(psum, 2);
      psum += __shfl_xor(psum, 4);
      psum += __shfl_xor(psum, 8);
      if (lm == 0) sred[rowl * 2 + wn] = psum;
    }
  }
  __syncthreads();
  if (tid < 128) {
    int g = tile * 128 + tid;
    if (g < S)
      spart[(size_t)hby * ((size_t)NB * S) + (size_t)b * S + g] = sred[tid * 2] + sred[tid * 2 + 1];
  }
}

// ---------------- combine 6 partials + bias + penalty ----------------
__global__ void combine_kernel(const float* __restrict__ sp, const int* __restrict__ spans,
                               const float* __restrict__ b_s, const int* __restrict__ lengths,
                               float* __restrict__ scores, int S) {
  int idx = blockIdx.x * 256 + threadIdx.x;
  if (idx >= NB * S) return;
  int b = idx / S, i = idx - b * S;
  size_t st = (size_t)NB * S;
  float v = b_s[0];
#pragma unroll
  for (int j = 0; j < 6; ++j) v += sp[j * st + idx];
  if (spans[2 * i + 1] >= lengths[b]) v += -1000000.0f;
  scores[idx] = v;
}

// ---------------- radix pivot (approx kth value) + zero band counter ----------------
__global__ __launch_bounds__(1024) void pivot_kernel(const float* __restrict__ scores,
                                                     const int* __restrict__ kptr, int S,
                                                     float* __restrict__ pivotf,
                                                     int* __restrict__ bandcount) {
  const int b = blockIdx.x;
  const int tid = threadIdx.x;
  const float* sc = scores + (size_t)b * S;
  const int k = kptr[0];
  __shared__ unsigned hist[256];
  __shared__ unsigned sh_prefix;
  __shared__ int sh_remaining;
  unsigned prefix = 0;
  int remaining = k;
  for (int round = 0; round < 4; ++round) {
    const int shift = 24 - 8 * round;
    if (tid < 256) hist[tid] = 0;
    __syncthreads();
    for (int i = tid; i < S; i += 1024) {
      unsigned key = f2key(sc[i]);
      if (round == 0 || (key >> (shift + 8)) == prefix)
        atomicAdd(&hist[(key >> shift) & 255u], 1u);
    }
    __syncthreads();
    if (tid == 0) {
      int cum = 0;
      for (int bin = 255; bin >= 0; --bin) {
        int c = (int)hist[bin];
        if (cum + c >= remaining) {
          sh_prefix = (prefix << 8) | (unsigned)bin;
          sh_remaining = remaining - cum;
          break;
        }
        cum += c;
      }
    }
    __syncthreads();
    prefix = sh_prefix;
    remaining = sh_remaining;
    __syncthreads();
  }
  if (tid == 0) {
    pivotf[b] = key2f(prefix);
    bandcount[b] = 0;
  }
}

// ---------------- band collect ----------------
__global__ void band_kernel(const float* __restrict__ scores, const float* __restrict__ pivotf,
                            int* __restrict__ bandcount, int* __restrict__ bandlist, int S) {
  int idx = blockIdx.x * 256 + threadIdx.x;
  if (idx >= NB * S) return;
  int b = idx / S, i = idx - b * S;
  if (fabsf(scores[idx] - pivotf[b]) <= BAND_TAU) {
    int slot = atomicAdd(&bandcount[b], 1);
    if (slot < BANDCAP) bandlist[b * BANDCAP + slot] = i;
  }
}

// ---------------- exact fp32 rescore of band spans ----------------
__global__ __launch_bounds__(256) void rescore_kernel(
    const float* __restrict__ emb, const int* __restrict__ spans,
    const float* __restrict__ W1, const float* __restrict__ w_s,
    const float* __restrict__ b_s, const int* __restrict__ lengths,
    const float* __restrict__ P, const float* __restrict__ Q, const float* __restrict__ R,
    const int* __restrict__ bandcount, const int* __restrict__ bandlist,
    float* __restrict__ scores, int S) {
  const int b = blockIdx.y;
  int cnt = bandcount[b];
  if (cnt > BANDCAP) cnt = BANDCAP;
  if ((int)blockIdx.x >= cnt) return;
  const int i = bandlist[b * BANDCAP + blockIdx.x];
  const int s = spans[2 * i], e = spans[2 * i + 1], wd = e - s;
  const int tid = threadIdx.x;
  __shared__ float prod[HH];
  __shared__ float red[256];
  for (int c = tid; c < HH; c += 256)
    prod[c] = emb[((size_t)b * NN + s) * HH + c] * emb[((size_t)b * NN + e) * HH + c];
  __syncthreads();
  const float* W1c = W1 + (size_t)(2 * HH) * HH;
  float psum = 0.f;
  for (int c0 = 0; c0 < HH; c0 += 256) {
    const int c = c0 + tid;
    float a = P[((size_t)b * NN + s) * HH + c] + Q[((size_t)b * NN + e) * HH + c] + R[(size_t)wd * HH + c];
    for (int k = 0; k < HH; ++k) a = fmaf(prod[k], W1c[(size_t)k * HH + c], a);
    psum = fmaf(gelu_f(a), w_s[c], psum);
  }
  red[tid] = psum;
  __syncthreads();
  for (int off = 128; off > 0; off >>= 1) {
    if (tid < off) red[tid] += red[tid + off];
    __syncthreads();
  }
  if (tid == 0) {
    float v = red[0] + b_s[0];
    if (e >= lengths[b]) v += -1000000.0f;
    scores[(size_t)b * S + i] = v;
  }
}

// ---------------- exact top-k (radix + index-ordered compaction) ----------------
__global__ __launch_bounds__(1024) void topk_kernel(
    const float* __restrict__ scores, const int* __restrict__ spans,
    const int* __restrict__ kptr, int S,
    float* __restrict__ out_spans, int* __restrict__ sel) {
  const int b = blockIdx.x;
  const int tid = threadIdx.x;
  const float* sc = scores + (size_t)b * S;
  const int k = kptr[0];
  __shared__ unsigned hist[256];
  __shared__ unsigned sh_prefix;
  __shared__ int sh_remaining;
  __shared__ int wave_eq[16], wave_sel[16];
  __shared__ int selbase, eqbase;
  unsigned prefix = 0;
  int remaining = k;
  for (int round = 0; round < 4; ++round) {
    const int shift = 24 - 8 * round;
    if (tid < 256) hist[tid] = 0;
    __syncthreads();
    for (int i = tid; i < S; i += 1024) {
      unsigned key = f2key(sc[i]);
      if (round == 0 || (key >> (shift + 8)) == prefix)
        atomicAdd(&hist[(key >> shift) & 255u], 1u);
    }
    __syncthreads();
    if (tid == 0) {
      int cum = 0;
      for (int bin = 255; bin >= 0; --bin) {
        int c = (int)hist[bin];
        if (cum + c >= remaining) {
          sh_prefix = (prefix << 8) | (unsigned)bin;
          sh_remaining = remaining - cum;
          break;
        }
        cum += c;
      }
    }
    __syncthreads();
    prefix = sh_prefix;
    remaining = sh_remaining;
    __syncthreads();
  }
  const unsigned pivot = prefix;
  const int m_eq = remaining;
  if (tid == 0) { selbase = 0; eqbase = 0; }
  __syncthreads();
  const int lane = tid & 63, wv = tid >> 6;
  for (int base = 0; base < S; base += 1024) {
    const int i = base + tid;
    const bool inb = (i < S);
    const unsigned key = inb ? f2key(sc[i]) : 0u;
    const bool gt = inb && (key > pivot);
    const bool eq = inb && (key == pivot);
    unsigned long long mm = __ballot(eq);
    int eqpre = __popcll(mm & ((1ull << lane) - 1ull));
    if (lane == 0) wave_eq[wv] = __popcll(mm);
    __syncthreads();
    int eqpref = 0, eqtot = 0;
#pragma unroll
    for (int w2 = 0; w2 < 16; ++w2) {
      int c = wave_eq[w2];
      if (w2 < wv) eqpref += c;
      eqtot += c;
    }
    const bool take_eq = eq && (eqbase + eqpref + eqpre < m_eq);
    const bool sf = gt || take_eq;
    unsigned long long sm = __ballot(sf);
    int spre = __popcll(sm & ((1ull << lane) - 1ull));
    if (lane == 0) wave_sel[wv] = __popcll(sm);
    __syncthreads();
    int spref = 0, stot = 0;
#pragma unroll
    for (int w2 = 0; w2 < 16; ++w2) {
      int c = wave_sel[w2];
      if (w2 < wv) spref += c;
      stot += c;
    }
    if (sf) {
      const int j = selbase + spref + spre;
      out_spans[(b * KTOP + j) * 2 + 0] = (float)spans[2 * i];
      out_spans[(b * KTOP + j) * 2 + 1] = (float)spans[2 * i + 1];
      sel[b * KTOP + j] = i;
    }
    __syncthreads();
    if (tid == 0) { selbase += stot; eqbase += eqtot; }
    __syncthreads();
  }
}

// ---------------- exact fp32 gather: h embeddings + score partials for selected spans ----------------
__global__ __launch_bounds__(256) void gather_kernel(
    const float* __restrict__ emb, const int* __restrict__ spans,
    const float* __restrict__ W1, const float* __restrict__ w_s,
    const float* __restrict__ P, const float* __restrict__ Q,
    const float* __restrict__ R, const int* __restrict__ sel,
    float* __restrict__ outh, float* __restrict__ spartg) {
  __shared__ float As[KT][ASTR];
  __shared__ float Bs[KT][BSTR];
  __shared__ int ssm[MT], eem[MT], wwm[MT], vvm[MT];
  const int tile = blockIdx.x;
  const int hb = blockIdx.y * NT;
  const int b = blockIdx.z;
  const int tid = threadIdx.x;
  const int th = tid & 31, tw = tid >> 5;
  if (tid < MT) {
    int s = 0, e = 0, valid = 0;
    int j = tile * MT + tid;
    if (j < KTOP) { int i = sel[b * KTOP + j]; s = spans[2 * i]; e = spans[2 * i + 1]; valid = 1; }
    ssm[tid] = s; eem[tid] = e; wwm[tid] = e - s; vvm[tid] = valid;
  }
  __syncthreads();
  const int m0 = tid >> 3, m1 = m0 + 32;
  const int d0 = (tid & 7) << 2;
  const size_t ebase = (size_t)b * NN * HH;
  const size_t rx0 = ebase + (size_t)ssm[m0] * HH;
  const size_t ry0 = ebase + (size_t)eem[m0] * HH;
  const size_t rx1 = ebase + (size_t)ssm[m1] * HH;
  const size_t ry1 = ebase + (size_t)eem[m1] * HH;
  const float* W1c = W1 + (size_t)(2 * HH) * HH;
  const int bc = (tid & 63) << 2;
  const int br = tid >> 6;
  float acc[8][8];
#pragma unroll
  for (int i = 0; i < 8; ++i)
#pragma unroll
    for (int j = 0; j < 8; ++j) acc[i][j] = 0.f;
  for (int kt = 0; kt < HH; kt += KT) {
    float4 x0 = *reinterpret_cast<const float4*>(emb + rx0 + kt + d0);
    float4 y0 = *reinterpret_cast<const float4*>(emb + ry0 + kt + d0);
    float4 x1 = *reinterpret_cast<const float4*>(emb + rx1 + kt + d0);
    float4 y1 = *reinterpret_cast<const float4*>(emb + ry1 + kt + d0);
    float4 bw[8];
#pragma unroll
    for (int r = 0; r < 8; ++r)
      bw[r] = *reinterpret_cast<const float4*>(W1c + (size_t)(kt + br + 4 * r) * HH + hb + bc);
    __syncthreads();
    As[d0 + 0][m0] = x0.x * y0.x; As[d0 + 1][m0] = x0.y * y0.y;
    As[d0 + 2][m0] = x0.z * y0.z; As[d0 + 3][m0] = x0.w * y0.w;
    As[d0 + 0][m1] = x1.x * y1.x; As[d0 + 1][m1] = x1.y * y1.y;
    As[d0 + 2][m1] = x1.z * y1.z; As[d0 + 3][m1] = x1.w * y1.w;
#pragma unroll
    for (int r = 0; r < 8; ++r)
      *reinterpret_cast<float4*>(&Bs[br + 4 * r][bc]) = bw[r];
    __syncthreads();
#pragma unroll
    for (int d = 0; d < KT; ++d) {
      const float4 a0 = *reinterpret_cast<const float4*>(&As[d][tw * 4]);
      const float4 a1 = *reinterpret_cast<const float4*>(&As[d][tw * 4 + 32]);
      const float4 b0 = *reinterpret_cast<const float4*>(&Bs[d][th * 4]);
      const float4 b1v = *reinterpret_cast<const float4*>(&Bs[d][th * 4 + 128]);
      const float av[8] = {a0.x, a0.y, a0.z, a0.w, a1.x, a1.y, a1.z, a1.w};
      const float bv[8] = {b0.x, b0.y, b0.z, b0.w, b1v.x, b1v.y, b1v.z, b1v.w};
#pragma unroll
      for (int mi = 0; mi < 8; ++mi)
#pragma unroll
        for (int ni = 0; ni < 8; ++ni)
          acc[mi][ni] = fmaf(av[mi], bv[ni], acc[mi][ni]);
    }
  }
  __syncthreads();
  float wv[8];
  {
    const float4 w0 = *reinterpret_cast<const float4*>(w_s + hb + th * 4);
    const float4 w1 = *reinterpret_cast<const float4*>(w_s + hb + th * 4 + 128);
    wv[0] = w0.x; wv[1] = w0.y; wv[2] = w0.z; wv[3] = w0.w;
    wv[4] = w1.x; wv[5] = w1.y; wv[6] = w1.z; wv[7] = w1.w;
  }
  float* sred = (float*)As;
#pragma unroll
  for (int mi = 0; mi < 8; ++mi) {
    const int m = tw * 4 + (mi & 3) + ((mi >> 2) << 5);
    float psum = 0.f;
    if (vvm[m]) {
      const int s = ssm[m], e = eem[m], wd = wwm[m];
      const float* Pp = P + ((size_t)b * NN + s) * HH + hb;
      const float* Qp = Q + ((size_t)b * NN + e) * HH + hb;
      const float* Rp = R + (size_t)wd * HH + hb;
      const float4 p0 = *reinterpret_cast<const float4*>(Pp + th * 4);
      const float4 p1 = *reinterpret_cast<const float4*>(Pp + th * 4 + 128);
      const float4 q0 = *reinterpret_cast<const float4*>(Qp + th * 4);
      const float4 q1 = *reinterpret_cast<const float4*>(Qp + th * 4 + 128);
      const float4 r0 = *reinterpret_cast<const float4*>(Rp + th * 4);
      const float4 r1 = *reinterpret_cast<const float4*>(Rp + th * 4 + 128);
      const float pz[8] = {p0.x + q0.x + r0.x, p0.y + q0.y + r0.y,
                           p0.z + q0.z + r0.z, p0.w + q0.w + r0.w,
                           p1.x + q1.x + r1.x, p1.y + q1.y + r1.y,
                           p1.z + q1.z + r1.z, p1.w + q1.w + r1.w};
      float gl[8];
#pragma unroll
      for (int ni = 0; ni < 8; ++ni) gl[ni] = gelu_f(acc[mi][ni] + pz[ni]);
      const int jj = tile * MT + m;
      float* op = outh + (size_t)(b * KTOP + jj) * HH + hb;
      *reinterpret_cast<float4*>(op + th * 4) = make_float4(gl[0], gl[1], gl[2], gl[3]);
      *reinterpret_cast<float4*>(op + th * 4 + 128) = make_float4(gl[4], gl[5], gl[6], gl[7]);
#pragma unroll
      for (int ni = 0; ni < 8; ++ni) psum = fmaf(gl[ni], wv[ni], psum);
    }
    sred[m * 33 + th] = psum;
  }
  __syncthreads();
  if (tid < MT) {
    float t = 0.f;
#pragma unroll
    for (int j = 0; j < 32; ++j) t += sred[tid * 33 + j];
    const int g = tile * MT + tid;
    if (g < KTOP)
      spartg[(size_t)blockIdx.y * (NB * KTOP) + b * KTOP + g] = t;
  }
}

// ---------------- final scores for selected spans ----------------
__global__ void score_fin_kernel(const float* __restrict__ spartg, const int* __restrict__ sel,
                                 const int* __restrict__ spans, const float* __restrict__ b_s,
                                 const int* __restrict__ lengths, float* __restrict__ out_scores) {
  int idx = blockIdx.x * 256 + threadIdx.x;
  if (idx >= NB * KTOP) return;
  int b = idx / KTOP;
  float v = spartg[idx] + spartg[NB * KTOP + idx] + spartg[2 * NB * KTOP + idx] + b_s[0];
  int i = sel[idx];
  if (spans[2 * i + 1] >= lengths[b]) v += -1000000.0f;
  out_scores[idx] = v;
}

extern "C" void kernel_launch(void* const* d_in, const int* in_sizes, int n_in,
                              void* d_out, int out_size, void* d_ws, size_t ws_size,
                              hipStream_t stream) {
  const float* emb = (const float*)d_in[0];
  const int* mask = (const int*)d_in[1];
  const int* spans = (const int*)d_in[2];
  const float* wemb = (const float*)d_in[3];
  const float* W1 = (const float*)d_in[4];
  const float* b1 = (const float*)d_in[5];
  const float* w_s = (const float*)d_in[6];
  const float* b_s = (const float*)d_in[7];
  const int* kptr = (const int*)d_in[8];
  const int S = in_sizes[2] / 2;
  float* out = (float*)d_out;

  // workspace carve (16-float aligned chunks)
  char* wp = (char*)d_ws;
  auto take = [&](size_t bytes) {
    char* p = wp;
    wp += (bytes + 63) & ~(size_t)63;
    return p;
  };
  float* Pb = (float*)take((size_t)NB * NN * HH * 4);
  float* Qb = (float*)take((size_t)NB * NN * HH * 4);
  float* Rb = (float*)take((size_t)MAXW * HH * 4);
  float* spart = (float*)take(6 * (size_t)NB * S * 4);
  float* scoresb = (float*)take((size_t)NB * S * 4);
  float* spartg = (float*)take(3 * (size_t)NB * KTOP * 4);
  float* pivotf = (float*)take(NB * 4);
  unsigned short* Bthi = (unsigned short*)take((size_t)HH * HH * 2);
  unsigned short* Btlo = (unsigned short*)take((size_t)HH * HH * 2);
  int* selb = (int*)take(NB * KTOP * 4);
  int* lengthsb = (int*)take(NB * 4);
  int* bandcount = (int*)take(NB * 4);
  int* bandlist = (int*)take(NB * BANDCAP * 4);

  const size_t OFF1 = (size_t)NB * KTOP * HH;    // embs
  const size_t OFF2 = OFF1 + (size_t)NB * KTOP;  // scores | spans

  const int tiles = (S + 127) / 128;

  len_kernel<<<dim3(1), dim3(256), 0, stream>>>(mask, lengthsb);
  r_kernel<<<dim3(MAXW), dim3(256), 0, stream>>>(wemb, W1, b1, Rb);
  prep_b_kernel<<<dim3(24, 6), dim3(256), 0, stream>>>(W1, Bthi, Btlo);
  pq_kernel<<<dim3((NB * NN) / MT, 6), dim3(256), 0, stream>>>(emb, W1, Pb, Qb);
  score_mfma_kernel<<<dim3(tiles, 6, NB), dim3(256), 0, stream>>>(
      emb, spans, Bthi, Btlo, w_s, Pb, Qb, Rb, spart, S);
  combine_kernel<<<dim3((NB * S + 255) / 256), dim3(256), 0, stream>>>(
      spart, spans, b_s, lengthsb, scoresb, S);
  pivot_kernel<<<dim3(NB), dim3(1024), 0, stream>>>(scoresb, kptr, S, pivotf, bandcount);
  band_kernel<<<dim3((NB * S + 255) / 256), dim3(256), 0, stream>>>(
      scoresb, pivotf, bandcount, bandlist, S);
  rescore_kernel<<<dim3(BANDCAP, NB), dim3(256), 0, stream>>>(
      emb, spans, W1, w_s, b_s, lengthsb, Pb, Qb, Rb, bandcount, bandlist, scoresb, S);
  topk_kernel<<<dim3(NB), dim3(1024), 0, stream>>>(scoresb, spans, kptr, S, out + OFF2, selb);
  gather_kernel<<<dim3((KTOP + MT - 1) / MT, 3, NB), dim3(256), 0, stream>>>(
      emb, spans, W1, w_s, Pb, Qb, Rb, selb, out, spartg);
  score_fin_kernel<<<dim3((NB * KTOP + 255) / 256), dim3(256), 0, stream>>>(
      spartg, selb, spans, b_s, lengthsb, out + OFF1);
}